// Round 2
// baseline (187.398 us; speedup 1.0000x reference)
//
#include <hip/hip_runtime.h>
#include <stdint.h>

#define NB 256
#define NQ 900
#define NC 256
#define TOPK 100
#define QC (NQ * NC)      // 230400
#define NBINS_S 4096
#define CAP 4096
#define KS 25             // sample-suffix target (x16 sampling -> ~400+ candidates)
#define SHIFT 18          // float bits >> 18 -> bin; scores in (0,1) -> bins < 4064

// fused = exp(-obj) * sigmoid(logit); classes >= 240 invalid (forced to ~0 in ref).
// Exact top-k: collect ALL elements with score >= threshold; if >=100 collected,
// the true top-100 is a subset. Threshold estimated from a 1/16 row sample;
// deterministic binary-search fallback guarantees correctness for any data.

__global__ __launch_bounds__(1024)
void postproc_kernel(const float* __restrict__ logits,
                     const float* __restrict__ obj,
                     const float* __restrict__ pboxes,
                     const float* __restrict__ tsz,
                     float* __restrict__ out)
{
    const int b = blockIdx.x;
    const int tid = threadIdx.x;
    const int wid = tid >> 6;
    const int lane = tid & 63;

    __shared__ unsigned int shist[NBINS_S];   // 16 KB
    __shared__ float eobj[NQ];                // 3.6 KB
    __shared__ unsigned int cbits[CAP];       // 16 KB
    __shared__ int cidx[CAP];                 // 16 KB
    __shared__ int activeQ[NQ];               // 3.6 KB
    __shared__ unsigned int part[1024];       // 4 KB
    __shared__ unsigned int part2[32];
    __shared__ int s_thrBin;
    __shared__ int s_cnt;
    __shared__ int s_nActive;
    __shared__ int s_c2;

    // ---- init ----
    for (int i = tid; i < NBINS_S; i += 1024) shist[i] = 0;
    if (tid == 0) { s_cnt = 0; s_nActive = 0; }
    if (tid < NQ) eobj[tid] = expf(-obj[b * NQ + tid]);
    __syncthreads();

    const float4* lg4 = (const float4*)(logits + (size_t)b * QC);

    // ---- pass A: sample rows q = 16j+8 (56 rows, 1/16), wave per row ----
    for (int j = wid; j < 56; j += 16) {
        int q = j * 16 + 8;
        if (lane < 60) {
            float eo = eobj[q];
            float4 v = lg4[(q << 6) + lane];
            float s0 = eo * (1.0f / (1.0f + expf(-v.x)));
            float s1 = eo * (1.0f / (1.0f + expf(-v.y)));
            float s2 = eo * (1.0f / (1.0f + expf(-v.z)));
            float s3 = eo * (1.0f / (1.0f + expf(-v.w)));
            atomicAdd(&shist[__float_as_uint(s0) >> SHIFT], 1u);
            atomicAdd(&shist[__float_as_uint(s1) >> SHIFT], 1u);
            atomicAdd(&shist[__float_as_uint(s2) >> SHIFT], 1u);
            atomicAdd(&shist[__float_as_uint(s3) >> SHIFT], 1u);
        }
    }
    __syncthreads();

    // ---- threshold bin: max T with sample_suffix(>=T) >= KS ----
    {
        unsigned int sum = 0;
        #pragma unroll
        for (int j = 0; j < 4; ++j) sum += shist[tid * 4 + j];
        part[tid] = sum;
    }
    __syncthreads();
    if (tid < 32) {
        unsigned int s2 = 0;
        #pragma unroll
        for (int j = 0; j < 32; ++j) s2 += part[tid * 32 + j];
        part2[tid] = s2;
    }
    __syncthreads();
    if (tid == 0) {
        int cum = 0;
        int sc = 31;
        while (sc > 0 && cum + (int)part2[sc] < KS) { cum += (int)part2[sc]; --sc; }
        int pc = sc * 32 + 31, plo = sc * 32;
        while (pc > plo && cum + (int)part[pc] < KS) { cum += (int)part[pc]; --pc; }
        int bin = pc * 4 + 3, blo = pc * 4;
        while (bin > blo && cum + (int)shist[bin] < KS) { cum += (int)shist[bin]; --bin; }
        s_thrBin = bin;
    }
    __syncthreads();
    unsigned int thrBits = (unsigned int)s_thrBin << SHIFT;

    // ---- active rows: score <= eobj, so skip rows with eobj < thr (exact) ----
    if (tid < NQ) {
        if (__float_as_uint(eobj[tid]) >= thrBits) {
            int p = atomicAdd(&s_nActive, 1);
            activeQ[p] = tid;
        }
    }
    __syncthreads();
    const int nA = s_nActive;

    // ---- pass B: collect candidates from active rows (wave per row) ----
    for (int j = wid; j < nA; j += 16) {
        int q = activeQ[j];
        if (lane < 60) {
            float eo = eobj[q];
            float4 v = lg4[(q << 6) + lane];
            #pragma unroll
            for (int j2 = 0; j2 < 4; ++j2) {
                float x = (j2 == 0) ? v.x : (j2 == 1) ? v.y : (j2 == 2) ? v.z : v.w;
                float s = eo * (1.0f / (1.0f + expf(-x)));
                unsigned int bits = __float_as_uint(s);
                if (bits >= thrBits) {
                    int p = atomicAdd(&s_cnt, 1);
                    if (p < CAP) {
                        cbits[p] = bits;
                        cidx[p] = (q << 8) + (lane << 2) + j2;
                    }
                }
            }
        }
    }
    __syncthreads();
    int M = s_cnt;

    // ---- fallback (exact, any data): binary-search threshold if sample misled ----
    if (M < TOPK || M > CAP) {
        int lo = 0, hi = NBINS_S - 1;   // count(>=0) = 216000 >= TOPK always
        while (lo < hi) {
            int mid = (lo + hi + 1) >> 1;
            unsigned int tb = (unsigned int)mid << SHIFT;
            if (tid == 0) s_c2 = 0;
            __syncthreads();
            int local = 0;
            for (int j = wid; j < NQ; j += 16) {
                if (__float_as_uint(eobj[j]) >= tb && lane < 60) {
                    float eo = eobj[j];
                    float4 v = lg4[(j << 6) + lane];
                    local += (__float_as_uint(eo * (1.0f / (1.0f + expf(-v.x)))) >= tb);
                    local += (__float_as_uint(eo * (1.0f / (1.0f + expf(-v.y)))) >= tb);
                    local += (__float_as_uint(eo * (1.0f / (1.0f + expf(-v.z)))) >= tb);
                    local += (__float_as_uint(eo * (1.0f / (1.0f + expf(-v.w)))) >= tb);
                }
            }
            atomicAdd(&s_c2, local);
            __syncthreads();
            if (s_c2 >= TOPK) lo = mid; else hi = mid - 1;
            __syncthreads();
        }
        unsigned int tb = (unsigned int)lo << SHIFT;
        if (tid == 0) s_cnt = 0;
        __syncthreads();
        for (int j = wid; j < NQ; j += 16) {
            if (__float_as_uint(eobj[j]) >= tb && lane < 60) {
                float eo = eobj[j];
                float4 v = lg4[(j << 6) + lane];
                #pragma unroll
                for (int j2 = 0; j2 < 4; ++j2) {
                    float x = (j2 == 0) ? v.x : (j2 == 1) ? v.y : (j2 == 2) ? v.z : v.w;
                    float s = eo * (1.0f / (1.0f + expf(-x)));
                    unsigned int bits = __float_as_uint(s);
                    if (bits >= tb) {
                        int p = atomicAdd(&s_cnt, 1);
                        if (p < CAP) {
                            cbits[p] = bits;
                            cidx[p] = (j << 8) + (lane << 2) + j2;
                        }
                    }
                }
            }
        }
        __syncthreads();
        M = s_cnt;
    }
    M = min(M, CAP);

    // ---- exact rank selection (desc score, tie -> lower index first) ----
    const float ih = tsz[b * 2 + 0];
    const float iw = tsz[b * 2 + 1];
    float* out_scores = out;
    float* out_labels = out + NB * TOPK;
    float* out_boxes  = out + 2 * NB * TOPK;

    for (int i = tid; i < M; i += 1024) {
        unsigned int mb = cbits[i];
        int mi = cidx[i];
        int rank = 0;
        for (int j = 0; j < M; ++j) {
            unsigned int obp = cbits[j];
            int oi = cidx[j];
            rank += (obp > mb) || (obp == mb && oi < mi);
        }
        if (rank < TOPK) {
            int q = mi >> 8;
            int c = mi & 255;
            out_scores[b * TOPK + rank] = __uint_as_float(mb);
            out_labels[b * TOPK + rank] = (float)c;
            const float* bp = pboxes + ((size_t)b * NQ + q) * 4;
            float cx = bp[0], cy = bp[1], w = bp[2], h = bp[3];
            float* dst = out_boxes + ((size_t)b * TOPK + rank) * 4;
            dst[0] = (cx - 0.5f * w) * iw;
            dst[1] = (cy - 0.5f * h) * ih;
            dst[2] = (cx + 0.5f * w) * iw;
            dst[3] = (cy + 0.5f * h) * ih;
        }
    }
}

extern "C" void kernel_launch(void* const* d_in, const int* in_sizes, int n_in,
                              void* d_out, int out_size, void* d_ws, size_t ws_size,
                              hipStream_t stream) {
    const float* logits = (const float*)d_in[0];
    const float* obj    = (const float*)d_in[1];
    const float* boxes  = (const float*)d_in[2];
    const float* tsz    = (const float*)d_in[3];
    float* out = (float*)d_out;
    hipLaunchKernelGGL(postproc_kernel, dim3(NB), dim3(1024), 0, stream,
                       logits, obj, boxes, tsz, out);
}

// Round 3
// 37.767 us; speedup vs baseline: 4.9620x; 4.9620x over previous
//
#include <hip/hip_runtime.h>
#include <stdint.h>

#define NB 256
#define NQ 900
#define NC 256
#define TOPK 100
#define QC (NQ * NC)      // 230400
#define NBINS_S 4096
#define CAP 4096
#define FCAP 512
#define KS 25             // sample-suffix target (x16 sampling -> ~400+ candidates)
#define SHIFT 18          // float bits >> 18 -> sample bin

// fused = exp(-obj) * sigmoid(logit); classes >= 240 invalid (forced ~0 in ref).
// Pass A (sampled, FAST math) estimates a collection threshold. Pass B (precise
// math, identical to rounds 1-2 which passed exactly) collects all elements with
// score bits >= thr. Exact kth via MSB radix-select over candidates, then O(n^2)
// rank over only the ~100 survivors. Binary-search fallback keeps correctness
// for any data distribution.

__device__ inline float fastsig(float x) {
    return __builtin_amdgcn_rcpf(1.0f + __expf(-x));
}

__global__ __launch_bounds__(1024)
void postproc_kernel(const float* __restrict__ logits,
                     const float* __restrict__ obj,
                     const float* __restrict__ pboxes,
                     const float* __restrict__ tsz,
                     float* __restrict__ out)
{
    const int b = blockIdx.x;
    const int tid = threadIdx.x;
    const int wid = tid >> 6;
    const int lane = tid & 63;

    __shared__ unsigned int pool[NBINS_S];    // 16 KB: shist, later fb/fi
    __shared__ float eobj[NQ];                // 3.6 KB
    __shared__ unsigned int cbits[CAP];       // 16 KB
    __shared__ int cidx[CAP];                 // 16 KB
    __shared__ int activeQ[NQ];               // 3.6 KB
    __shared__ unsigned int part[1024];       // 4 KB: sample scan, later rhist/rsuf
    __shared__ unsigned int part2[32];
    __shared__ int s_thrBin, s_cnt, s_nActive, s_c2;
    __shared__ int s_dig, s_above, s_nfin;

    unsigned int* shist = pool;

    // ---- init ----
    for (int i = tid; i < NBINS_S; i += 1024) shist[i] = 0;
    if (tid == 0) { s_cnt = 0; s_nActive = 0; }
    if (tid < NQ) eobj[tid] = expf(-obj[b * NQ + tid]);
    __syncthreads();

    const float4* lg4 = (const float4*)(logits + (size_t)b * QC);

    // ---- pass A: sample rows q = 16j+8 (56 rows), wave per row, FAST score ----
    for (int j = wid; j < 56; j += 16) {
        int q = j * 16 + 8;
        if (lane < 60) {
            float eo = eobj[q];
            float4 v = lg4[(q << 6) + lane];
            float s0 = eo * fastsig(v.x);
            float s1 = eo * fastsig(v.y);
            float s2 = eo * fastsig(v.z);
            float s3 = eo * fastsig(v.w);
            atomicAdd(&shist[__float_as_uint(s0) >> SHIFT], 1u);
            atomicAdd(&shist[__float_as_uint(s1) >> SHIFT], 1u);
            atomicAdd(&shist[__float_as_uint(s2) >> SHIFT], 1u);
            atomicAdd(&shist[__float_as_uint(s3) >> SHIFT], 1u);
        }
    }
    __syncthreads();

    // ---- sample threshold: max bin with suffix >= KS ----
    {
        unsigned int sum = 0;
        #pragma unroll
        for (int j = 0; j < 4; ++j) sum += shist[tid * 4 + j];
        part[tid] = sum;
    }
    __syncthreads();
    if (tid < 32) {
        unsigned int s2 = 0;
        #pragma unroll
        for (int j = 0; j < 32; ++j) s2 += part[tid * 32 + j];
        part2[tid] = s2;
    }
    __syncthreads();
    if (tid == 0) {
        int cum = 0;
        int sc = 31;
        while (sc > 0 && cum + (int)part2[sc] < KS) { cum += (int)part2[sc]; --sc; }
        int pc = sc * 32 + 31, plo = sc * 32;
        while (pc > plo && cum + (int)part[pc] < KS) { cum += (int)part[pc]; --pc; }
        int bin = pc * 4 + 3, blo = pc * 4;
        while (bin > blo && cum + (int)shist[bin] < KS) { cum += (int)shist[bin]; --bin; }
        s_thrBin = bin;
    }
    __syncthreads();
    unsigned int thrBits = (unsigned int)s_thrBin << SHIFT;

    // ---- active rows (exact bound: score <= eobj) ----
    if (tid < NQ) {
        if (__float_as_uint(eobj[tid]) >= thrBits) {
            int p = atomicAdd(&s_nActive, 1);
            activeQ[p] = tid;
        }
    }
    __syncthreads();
    const int nA = s_nActive;

    // ---- pass B: collect candidates (PRECISE math — defines outputs) ----
    for (int j = wid; j < nA; j += 16) {
        int q = activeQ[j];
        if (lane < 60) {
            float eo = eobj[q];
            float4 v = lg4[(q << 6) + lane];
            #pragma unroll
            for (int j2 = 0; j2 < 4; ++j2) {
                float x = (j2 == 0) ? v.x : (j2 == 1) ? v.y : (j2 == 2) ? v.z : v.w;
                float s = eo * (1.0f / (1.0f + expf(-x)));
                unsigned int bits = __float_as_uint(s);
                if (bits >= thrBits) {
                    int p = atomicAdd(&s_cnt, 1);
                    if (p < CAP) {
                        cbits[p] = bits;
                        cidx[p] = (q << 8) + (lane << 2) + j2;
                    }
                }
            }
        }
    }
    __syncthreads();
    int M = s_cnt;

    // ---- fallback (exact, any data): binary-search threshold ----
    if (M < TOPK || M > CAP) {
        int lo = 0, hi = NBINS_S - 1;
        while (lo < hi) {
            int mid = (lo + hi + 1) >> 1;
            unsigned int tb = (unsigned int)mid << SHIFT;
            if (tid == 0) s_c2 = 0;
            __syncthreads();
            int local = 0;
            for (int j = wid; j < NQ; j += 16) {
                if (__float_as_uint(eobj[j]) >= tb && lane < 60) {
                    float eo = eobj[j];
                    float4 v = lg4[(j << 6) + lane];
                    local += (__float_as_uint(eo * (1.0f / (1.0f + expf(-v.x)))) >= tb);
                    local += (__float_as_uint(eo * (1.0f / (1.0f + expf(-v.y)))) >= tb);
                    local += (__float_as_uint(eo * (1.0f / (1.0f + expf(-v.z)))) >= tb);
                    local += (__float_as_uint(eo * (1.0f / (1.0f + expf(-v.w)))) >= tb);
                }
            }
            atomicAdd(&s_c2, local);
            __syncthreads();
            if (s_c2 >= TOPK) lo = mid; else hi = mid - 1;
            __syncthreads();
        }
        unsigned int tb = (unsigned int)lo << SHIFT;
        thrBits = tb;
        if (tid == 0) s_cnt = 0;
        __syncthreads();
        for (int j = wid; j < NQ; j += 16) {
            if (__float_as_uint(eobj[j]) >= tb && lane < 60) {
                float eo = eobj[j];
                float4 v = lg4[(j << 6) + lane];
                #pragma unroll
                for (int j2 = 0; j2 < 4; ++j2) {
                    float x = (j2 == 0) ? v.x : (j2 == 1) ? v.y : (j2 == 2) ? v.z : v.w;
                    float s = eo * (1.0f / (1.0f + expf(-x)));
                    unsigned int bits = __float_as_uint(s);
                    if (bits >= tb) {
                        int p = atomicAdd(&s_cnt, 1);
                        if (p < CAP) {
                            cbits[p] = bits;
                            cidx[p] = (j << 8) + (lane << 2) + j2;
                        }
                    }
                }
            }
        }
        __syncthreads();
        M = s_cnt;
    }
    M = min(M, CAP);

    // ---- radix-select: exact TOPK-th largest bits among cbits[0..M) ----
    unsigned int* rhist = part;          // 256
    unsigned int* rsuf  = part + 256;    // 256
    unsigned int prefixVal = 0;
    int need = TOPK;
    int startShift = 24;
    // all candidates share high byte 0x3F when thr >= 0.5 (scores <= 1.0)
    if ((thrBits >> 24) == 0x3Fu) { prefixVal = 0x3F000000u; startShift = 16; }
    for (int shift = startShift; shift >= 0; shift -= 8) {
        if (tid < 256) rhist[tid] = 0;
        __syncthreads();
        unsigned int pmask = (shift >= 24) ? 0u : (0xFFFFFFFFu << (shift + 8));
        for (int i = tid; i < M; i += 1024) {
            unsigned int bb = cbits[i];
            if ((bb & pmask) == (prefixVal & pmask))
                atomicAdd(&rhist[(bb >> shift) & 255], 1u);
        }
        __syncthreads();
        // one-wave suffix scan of 256 bins (4 bins per lane, shfl across lanes)
        if (tid < 64) {
            unsigned int h0 = rhist[tid * 4 + 0];
            unsigned int h1 = rhist[tid * 4 + 1];
            unsigned int h2 = rhist[tid * 4 + 2];
            unsigned int h3 = rhist[tid * 4 + 3];
            unsigned int loc = h0 + h1 + h2 + h3;
            unsigned int suf = loc;
            #pragma unroll
            for (int d = 1; d < 64; d <<= 1) {
                unsigned int o = __shfl_down(suf, d);
                suf += (tid + d < 64) ? o : 0u;
            }
            unsigned int above = suf - loc;    // sum of lanes > tid
            rsuf[tid * 4 + 3] = above + h3;
            rsuf[tid * 4 + 2] = above + h3 + h2;
            rsuf[tid * 4 + 1] = above + h3 + h2 + h1;
            rsuf[tid * 4 + 0] = above + h3 + h2 + h1 + h0;
        }
        __syncthreads();
        if (tid < 256) {
            int sv = (int)rsuf[tid];
            int sa = (tid == 255) ? 0 : (int)rsuf[tid + 1];
            if (sv >= need && sa < need) { s_dig = tid; s_above = sa; }
        }
        __syncthreads();
        prefixVal |= ((unsigned int)s_dig) << shift;
        need -= s_above;
    }
    const unsigned int kth = prefixVal;   // exact 100th-largest score bits

    // ---- compact survivors (bits >= kth): n = (#>kth) + (#==kth) >= 100 ----
    unsigned int* fb = pool;              // FCAP
    int* fi = (int*)(pool + FCAP);        // FCAP
    if (tid == 0) s_nfin = 0;
    __syncthreads();
    for (int i = tid; i < M; i += 1024) {
        unsigned int bb = cbits[i];
        if (bb >= kth) {
            int p = atomicAdd(&s_nfin, 1);
            if (p < FCAP) { fb[p] = bb; fi[p] = cidx[i]; }
        }
    }
    __syncthreads();
    const int n = min(s_nfin, FCAP);

    // ---- exact rank over survivors (desc bits, tie -> lower index) ----
    const float ih = tsz[b * 2 + 0];
    const float iw = tsz[b * 2 + 1];
    float* out_scores = out;
    float* out_labels = out + NB * TOPK;
    float* out_boxes  = out + 2 * NB * TOPK;

    for (int i = tid; i < n; i += 1024) {
        unsigned int mb = fb[i];
        int mi = fi[i];
        int rank = 0;
        for (int j = 0; j < n; ++j) {
            unsigned int ob = fb[j];
            int oi = fi[j];
            rank += (ob > mb) || (ob == mb && oi < mi);
        }
        if (rank < TOPK) {
            int q = mi >> 8;
            int c = mi & 255;
            out_scores[b * TOPK + rank] = __uint_as_float(mb);
            out_labels[b * TOPK + rank] = (float)c;
            const float* bp = pboxes + ((size_t)b * NQ + q) * 4;
            float cx = bp[0], cy = bp[1], w = bp[2], h = bp[3];
            float* dst = out_boxes + ((size_t)b * TOPK + rank) * 4;
            dst[0] = (cx - 0.5f * w) * iw;
            dst[1] = (cy - 0.5f * h) * ih;
            dst[2] = (cx + 0.5f * w) * iw;
            dst[3] = (cy + 0.5f * h) * ih;
        }
    }
}

extern "C" void kernel_launch(void* const* d_in, const int* in_sizes, int n_in,
                              void* d_out, int out_size, void* d_ws, size_t ws_size,
                              hipStream_t stream) {
    const float* logits = (const float*)d_in[0];
    const float* obj    = (const float*)d_in[1];
    const float* boxes  = (const float*)d_in[2];
    const float* tsz    = (const float*)d_in[3];
    float* out = (float*)d_out;
    hipLaunchKernelGGL(postproc_kernel, dim3(NB), dim3(1024), 0, stream,
                       logits, obj, boxes, tsz, out);
}